// Round 1
// baseline (544.887 us; speedup 1.0000x reference)
//
#include <hip/hip_runtime.h>

// Problem constants (from setup_inputs: B=8, N_t=14, N_f=72, d_model=256, h=8, d_rpe=32)
#define B_    8
#define N_    1008
#define D_    256
#define H_    8
#define DK_   32
#define NT_   14
#define NF_   72
#define RF_   143          // 2*NF-1
#define TAB_  3861         // (2*NT-1)*(2*NF-1)
#define DR_   32
#define NFREQ_ 8
#define BND_  (B_*N_*D_)   // 2064384 elements per (B,N,D) tensor

// ---------------------------------------------------------------------------
// Kernel 1: RPE table (3861 x 8 heads) + additive index arrays aq[N], bk[N]
//   bias(h,q,k) = table[h][ aq[q] + bk[k] ]
// ---------------------------------------------------------------------------
__global__ void rpe_table_kernel(const float* __restrict__ W_rpe,
                                 const int* __restrict__ t_q, const int* __restrict__ f_q,
                                 const int* __restrict__ t_k, const int* __restrict__ f_k,
                                 float* __restrict__ table, int* __restrict__ aq,
                                 int* __restrict__ bk)
{
    int idx = blockIdx.x * blockDim.x + threadIdx.x;
    if (idx < N_) {
        aq[idx] = t_q[idx] * RF_ + f_q[idx];
        bk[idx] = (NT_ - 1) * RF_ + (NF_ - 1) - (t_k[idx] * RF_ + f_k[idx]);
    }
    if (idx < TAB_) {
        int it = idx / RF_;
        int jf = idx - it * RF_;
        float dt = (float)(it - (NT_ - 1)) / (float)(NT_ - 1);
        float df = (float)(jf - (NF_ - 1)) / (float)(NF_ - 1);
        float enc[DR_];
#pragma unroll
        for (int i = 0; i < NFREQ_; i++) {
            float fr = expf(-9.210340371976184f * (float)i / (float)NFREQ_); // ln(10000)
            float at = dt * fr, af = df * fr;
            enc[i]            = sinf(at);
            enc[NFREQ_ + i]   = cosf(at);
            enc[2*NFREQ_ + i] = sinf(af);
            enc[3*NFREQ_ + i] = cosf(af);
        }
#pragma unroll
        for (int hh = 0; hh < H_; hh++) {
            float s = 0.f;
#pragma unroll
            for (int j = 0; j < DR_; j++) s += enc[j] * W_rpe[hh * DR_ + j];
            table[hh * TAB_ + idx] = s;
        }
    }
}

// ---------------------------------------------------------------------------
// Kernel 2: fp32 tiled GEMM  out = A @ W^T  (A: Mx256 row-major, W: 256x256 row-major)
// MODE 0: head-split epilogue out[((b*H+h)*N+q)*DK+d], with scale (used for Q/K/V)
// MODE 1: plain row-major out[m*256+n]                     (used for final W_o)
// 64x64 tile, 256 threads, 4x4 microtile, K-chunks of 32, transposed LDS for
// float4 compute reads (<=2-way bank aliasing on reads = free).
// ---------------------------------------------------------------------------
template <int MODE>
__global__ __launch_bounds__(256) void gemm_tile(const float* __restrict__ A,
                                                 const float* __restrict__ W,
                                                 float* __restrict__ out, float scale)
{
    __shared__ float AsT[32][68];
    __shared__ float BsT[32][68];
    const int tid = threadIdx.x;
    const int tx = tid & 15, ty = tid >> 4;
    const int m0 = blockIdx.x * 64;
    const int n0 = blockIdx.y * 64;
    const int lr = tid >> 2;           // 0..63 tile row
    const int lc = (tid & 3) * 8;      // 0,8,16,24

    float acc[4][4] = {};
    for (int k0 = 0; k0 < D_; k0 += 32) {
        float4 a0 = *(const float4*)&A[(size_t)(m0 + lr) * D_ + k0 + lc];
        float4 a1 = *(const float4*)&A[(size_t)(m0 + lr) * D_ + k0 + lc + 4];
        float4 b0 = *(const float4*)&W[(size_t)(n0 + lr) * D_ + k0 + lc];
        float4 b1 = *(const float4*)&W[(size_t)(n0 + lr) * D_ + k0 + lc + 4];
        __syncthreads();   // protect previous iteration's LDS reads
        AsT[lc+0][lr]=a0.x; AsT[lc+1][lr]=a0.y; AsT[lc+2][lr]=a0.z; AsT[lc+3][lr]=a0.w;
        AsT[lc+4][lr]=a1.x; AsT[lc+5][lr]=a1.y; AsT[lc+6][lr]=a1.z; AsT[lc+7][lr]=a1.w;
        BsT[lc+0][lr]=b0.x; BsT[lc+1][lr]=b0.y; BsT[lc+2][lr]=b0.z; BsT[lc+3][lr]=b0.w;
        BsT[lc+4][lr]=b1.x; BsT[lc+5][lr]=b1.y; BsT[lc+6][lr]=b1.z; BsT[lc+7][lr]=b1.w;
        __syncthreads();
#pragma unroll
        for (int kk = 0; kk < 32; kk++) {
            float4 av = *(const float4*)&AsT[kk][ty * 4];
            float4 bv = *(const float4*)&BsT[kk][tx * 4];
            acc[0][0] += av.x*bv.x; acc[0][1] += av.x*bv.y; acc[0][2] += av.x*bv.z; acc[0][3] += av.x*bv.w;
            acc[1][0] += av.y*bv.x; acc[1][1] += av.y*bv.y; acc[1][2] += av.y*bv.z; acc[1][3] += av.y*bv.w;
            acc[2][0] += av.z*bv.x; acc[2][1] += av.z*bv.y; acc[2][2] += av.z*bv.z; acc[2][3] += av.z*bv.w;
            acc[3][0] += av.w*bv.x; acc[3][1] += av.w*bv.y; acc[3][2] += av.w*bv.z; acc[3][3] += av.w*bv.w;
        }
    }
#pragma unroll
    for (int i = 0; i < 4; i++) {
        const int m = m0 + ty * 4 + i;
        float4 v;
        v.x = acc[i][0]*scale; v.y = acc[i][1]*scale; v.z = acc[i][2]*scale; v.w = acc[i][3]*scale;
        if (MODE == 0) {
            const int bb = m / N_;
            const int q  = m - bb * N_;
            const int n  = n0 + tx * 4;       // 4-aligned -> stays within one head (DK=32)
            const int hh = n >> 5;
            const int d  = n & 31;
            *(float4*)&out[(((size_t)bb * H_ + hh) * N_ + q) * DK_ + d] = v;
        } else {
            *(float4*)&out[(size_t)m * D_ + n0 + tx * 4] = v;
        }
    }
}

// ---------------------------------------------------------------------------
// Kernel 3: flash attention with RPE bias.
// grid = (B*H, ceil(N/64)); block = 256 (16x16), per-thread 4 q-rows x 4 k-cols
// of S, 4 q-rows x 2 dk-cols of O. Per-head bias table lives in LDS.
// ---------------------------------------------------------------------------
__global__ __launch_bounds__(256) void attn_kernel(const float* __restrict__ Q,
                                                   const float* __restrict__ K,
                                                   const float* __restrict__ V,
                                                   const float* __restrict__ table,
                                                   const int* __restrict__ aq,
                                                   const int* __restrict__ bk,
                                                   float* __restrict__ AO)
{
    __shared__ float QsT[DK_][68];   // [dim][q-row]
    __shared__ float KsT[DK_][68];   // [dim][k-row]
    __shared__ float VsT[DK_][68];   // [dk-col][k-row]
    __shared__ float Ps[64][68];     // [q-row][k-col]
    __shared__ float tab_s[TAB_];    // per-head bias table (15.4 KB)

    const int tid = threadIdx.x;
    const int tx = tid & 15, ty = tid >> 4;
    const int bh = blockIdx.x;            // b*H + h
    const int q0 = blockIdx.y * 64;
    const int b  = bh >> 3;
    const int hh = bh & 7;
    const float* Qb = Q + (size_t)bh * N_ * DK_;
    const float* Kb = K + (size_t)bh * N_ * DK_;
    const float* Vb = V + (size_t)bh * N_ * DK_;
    const float* th = table + hh * TAB_;

    for (int i = tid; i < TAB_; i += 256) tab_s[i] = th[i];

    const int lr = tid >> 2;          // 0..63
    const int lc = (tid & 3) * 8;     // 0,8,16,24
    {   // stage Q tile (transposed)
        int q = q0 + lr;
        float4 x0 = make_float4(0,0,0,0), x1 = make_float4(0,0,0,0);
        if (q < N_) {
            x0 = *(const float4*)&Qb[q * DK_ + lc];
            x1 = *(const float4*)&Qb[q * DK_ + lc + 4];
        }
        QsT[lc+0][lr]=x0.x; QsT[lc+1][lr]=x0.y; QsT[lc+2][lr]=x0.z; QsT[lc+3][lr]=x0.w;
        QsT[lc+4][lr]=x1.x; QsT[lc+5][lr]=x1.y; QsT[lc+6][lr]=x1.z; QsT[lc+7][lr]=x1.w;
    }
    int aqr[4];
#pragma unroll
    for (int i = 0; i < 4; i++) {
        int q = q0 + ty * 4 + i;
        aqr[i] = (q < N_) ? aq[q] : 0;
    }
    float m_[4], l_[4], O[4][2];
#pragma unroll
    for (int i = 0; i < 4; i++) { m_[i] = -1e30f; l_[i] = 0.f; O[i][0] = 0.f; O[i][1] = 0.f; }

    const int nkt = (N_ + 63) >> 6;   // 16
    for (int kt = 0; kt < nkt; kt++) {
        const int k0 = kt << 6;
        int k = k0 + lr;
        float4 kx0 = make_float4(0,0,0,0), kx1 = kx0, vx0 = kx0, vx1 = kx0;
        if (k < N_) {
            kx0 = *(const float4*)&Kb[k * DK_ + lc];
            kx1 = *(const float4*)&Kb[k * DK_ + lc + 4];
            vx0 = *(const float4*)&Vb[k * DK_ + lc];
            vx1 = *(const float4*)&Vb[k * DK_ + lc + 4];
        }
        int bkr[4];
#pragma unroll
        for (int j = 0; j < 4; j++) {
            int kc = k0 + tx * 4 + j;
            bkr[j] = (kc < N_) ? bk[kc] : 0;
        }
        KsT[lc+0][lr]=kx0.x; KsT[lc+1][lr]=kx0.y; KsT[lc+2][lr]=kx0.z; KsT[lc+3][lr]=kx0.w;
        KsT[lc+4][lr]=kx1.x; KsT[lc+5][lr]=kx1.y; KsT[lc+6][lr]=kx1.z; KsT[lc+7][lr]=kx1.w;
        VsT[lc+0][lr]=vx0.x; VsT[lc+1][lr]=vx0.y; VsT[lc+2][lr]=vx0.z; VsT[lc+3][lr]=vx0.w;
        VsT[lc+4][lr]=vx1.x; VsT[lc+5][lr]=vx1.y; VsT[lc+6][lr]=vx1.z; VsT[lc+7][lr]=vx1.w;
        __syncthreads();   // (A) staged tiles visible (first iter: also Q + table)

        float S[4][4] = {};
#pragma unroll
        for (int kk = 0; kk < DK_; kk++) {
            float4 av = *(const float4*)&QsT[kk][ty * 4];
            float4 bv = *(const float4*)&KsT[kk][tx * 4];
            S[0][0] += av.x*bv.x; S[0][1] += av.x*bv.y; S[0][2] += av.x*bv.z; S[0][3] += av.x*bv.w;
            S[1][0] += av.y*bv.x; S[1][1] += av.y*bv.y; S[1][2] += av.y*bv.z; S[1][3] += av.y*bv.w;
            S[2][0] += av.z*bv.x; S[2][1] += av.z*bv.y; S[2][2] += av.z*bv.z; S[2][3] += av.z*bv.w;
            S[3][0] += av.w*bv.x; S[3][1] += av.w*bv.y; S[3][2] += av.w*bv.z; S[3][3] += av.w*bv.w;
        }
        // bias + k-mask (Q already carries 1/sqrt(dk); bias is unscaled per reference)
#pragma unroll
        for (int i = 0; i < 4; i++) {
#pragma unroll
            for (int j = 0; j < 4; j++) {
                int kc = k0 + tx * 4 + j;
                if (kc < N_) S[i][j] += tab_s[aqr[i] + bkr[j]];
                else         S[i][j] = -1e30f;
            }
        }
        // online softmax (row group = 16 contiguous lanes; xor-shuffle stays in group)
#pragma unroll
        for (int i = 0; i < 4; i++) {
            float rm = fmaxf(fmaxf(S[i][0], S[i][1]), fmaxf(S[i][2], S[i][3]));
#pragma unroll
            for (int off = 1; off < 16; off <<= 1) rm = fmaxf(rm, __shfl_xor(rm, off, 64));
            float mn = fmaxf(m_[i], rm);
            float al = __expf(m_[i] - mn);
            float4 p;
            p.x = __expf(S[i][0] - mn);
            p.y = __expf(S[i][1] - mn);
            p.z = __expf(S[i][2] - mn);
            p.w = __expf(S[i][3] - mn);
            *(float4*)&Ps[ty * 4 + i][tx * 4] = p;
            float rs = p.x + p.y + p.z + p.w;
#pragma unroll
            for (int off = 1; off < 16; off <<= 1) rs += __shfl_xor(rs, off, 64);
            l_[i] = l_[i] * al + rs;
            m_[i] = mn;
            O[i][0] *= al; O[i][1] *= al;
        }
        __syncthreads();   // (B) Ps visible
        // O += P @ V   (P reads broadcast; V float4 rows)
#pragma unroll
        for (int jc = 0; jc < 64; jc += 4) {
            float4 p0 = *(const float4*)&Ps[ty * 4 + 0][jc];
            float4 p1 = *(const float4*)&Ps[ty * 4 + 1][jc];
            float4 p2 = *(const float4*)&Ps[ty * 4 + 2][jc];
            float4 p3 = *(const float4*)&Ps[ty * 4 + 3][jc];
            float4 va = *(const float4*)&VsT[tx * 2 + 0][jc];
            float4 vb = *(const float4*)&VsT[tx * 2 + 1][jc];
            O[0][0] += p0.x*va.x + p0.y*va.y + p0.z*va.z + p0.w*va.w;
            O[0][1] += p0.x*vb.x + p0.y*vb.y + p0.z*vb.z + p0.w*vb.w;
            O[1][0] += p1.x*va.x + p1.y*va.y + p1.z*va.z + p1.w*va.w;
            O[1][1] += p1.x*vb.x + p1.y*vb.y + p1.z*vb.z + p1.w*vb.w;
            O[2][0] += p2.x*va.x + p2.y*va.y + p2.z*va.z + p2.w*va.w;
            O[2][1] += p2.x*vb.x + p2.y*vb.y + p2.z*vb.z + p2.w*vb.w;
            O[3][0] += p3.x*va.x + p3.y*va.y + p3.z*va.z + p3.w*va.w;
            O[3][1] += p3.x*vb.x + p3.y*vb.y + p3.z*vb.z + p3.w*vb.w;
        }
        __syncthreads();   // (C) PV done before next tile overwrites LDS
    }
    // epilogue: attnout layout (B, N, H*DK) for the W_o GEMM
#pragma unroll
    for (int i = 0; i < 4; i++) {
        int q = q0 + ty * 4 + i;
        if (q < N_) {
            float inv = 1.0f / l_[i];
            float2 o;
            o.x = O[i][0] * inv;
            o.y = O[i][1] * inv;
            *(float2*)&AO[((size_t)b * N_ + q) * D_ + hh * DK_ + tx * 2] = o;
        }
    }
}

// ---------------------------------------------------------------------------
extern "C" void kernel_launch(void* const* d_in, const int* in_sizes, int n_in,
                              void* d_out, int out_size, void* d_ws, size_t ws_size,
                              hipStream_t stream)
{
    const float* q_tokens = (const float*)d_in[0];
    const float* k_tokens = (const float*)d_in[1];
    const float* v_tokens = (const float*)d_in[2];
    const int*   t_q      = (const int*)d_in[3];
    const int*   f_q      = (const int*)d_in[4];
    const int*   t_k      = (const int*)d_in[5];
    const int*   f_k      = (const int*)d_in[6];
    // d_in[7]=N_t, d_in[8]=N_f (hardcoded as NT_/NF_)
    const float* W_q   = (const float*)d_in[9];
    const float* W_k   = (const float*)d_in[10];
    const float* W_v   = (const float*)d_in[11];
    const float* W_o   = (const float*)d_in[12];
    const float* W_rpe = (const float*)d_in[13];
    float* out = (float*)d_out;

    // workspace layout (fp32): Q,K,V (B,H,N,DK) + attnout (B,N,D) + table + idx
    float* ws    = (float*)d_ws;
    float* Qp    = ws;                 // BND_
    float* Kp    = Qp + BND_;          // BND_
    float* Vp    = Kp + BND_;          // BND_
    float* AO    = Vp + BND_;          // BND_
    float* table = AO + BND_;          // H_*TAB_ = 30888
    int*   aq    = (int*)(table + H_ * TAB_);  // N_
    int*   bk    = aq + 1024;                  // N_
    // total ~33.2 MB

    rpe_table_kernel<<<dim3(16), dim3(256), 0, stream>>>(W_rpe, t_q, f_q, t_k, f_k,
                                                         table, aq, bk);

    const float qscale = 0.17677669529663687f;  // 1/sqrt(32)
    gemm_tile<0><<<dim3(126, 4), dim3(256), 0, stream>>>(q_tokens, W_q, Qp, qscale);
    gemm_tile<0><<<dim3(126, 4), dim3(256), 0, stream>>>(k_tokens, W_k, Kp, 1.0f);
    gemm_tile<0><<<dim3(126, 4), dim3(256), 0, stream>>>(v_tokens, W_v, Vp, 1.0f);

    attn_kernel<<<dim3(B_ * H_, (N_ + 63) / 64), dim3(256), 0, stream>>>(Qp, Kp, Vp,
                                                                         table, aq, bk, AO);

    gemm_tile<1><<<dim3(126, 4), dim3(256), 0, stream>>>(AO, W_o, out, 1.0f);
}

// Round 2
// 175.459 us; speedup vs baseline: 3.1055x; 3.1055x over previous
//
#include <hip/hip_runtime.h>

// Problem constants (B=8, N_t=14, N_f=72, d_model=256, h=8, d_rpe=32)
#define B_    8
#define N_    1008
#define D_    256
#define H_    8
#define DK_   32
#define NT_   14
#define NF_   72
#define RF_   143          // 2*NF-1
#define TAB_  3861         // (2*NT-1)*(2*NF-1)
#define NFREQ_ 8
#define BND_  (B_*N_*D_)   // 2064384

typedef _Float16 half8_t __attribute__((ext_vector_type(8)));
typedef _Float16 half4_t __attribute__((ext_vector_type(4)));
typedef float    f32x4   __attribute__((ext_vector_type(4)));

// ---------------------------------------------------------------------------
// K1: tokens fp32 -> fp16 (3 tensors via blockIdx.y). grid (2016,3) x 256: exact.
// ---------------------------------------------------------------------------
__global__ void cvt_tokens(const float* __restrict__ a, const float* __restrict__ b,
                           const float* __restrict__ c, _Float16* __restrict__ oa,
                           _Float16* __restrict__ ob, _Float16* __restrict__ oc)
{
    const float* src; _Float16* dst;
    if (blockIdx.y == 0)      { src = a; dst = oa; }
    else if (blockIdx.y == 1) { src = b; dst = ob; }
    else                      { src = c; dst = oc; }
    size_t i = ((size_t)blockIdx.x * 256 + threadIdx.x) * 4;
    float4 v = *(const float4*)&src[i];
    half4_t h = { (_Float16)v.x, (_Float16)v.y, (_Float16)v.z, (_Float16)v.w };
    *(half4_t*)&dst[i] = h;
}

// ---------------------------------------------------------------------------
// K2: RPE table (3861 x 8 heads, fp16) + additive index arrays aq[N], bk[N]
//   bias(h,q,k) = table[h][ aq[q] + bk[k] ]   (clip in ref is a no-op)
// ---------------------------------------------------------------------------
__global__ void rpe_table_kernel(const float* __restrict__ W_rpe,
                                 const int* __restrict__ t_q, const int* __restrict__ f_q,
                                 const int* __restrict__ t_k, const int* __restrict__ f_k,
                                 _Float16* __restrict__ table, int* __restrict__ aq,
                                 int* __restrict__ bk)
{
    int idx = blockIdx.x * blockDim.x + threadIdx.x;
    if (idx < N_) {
        aq[idx] = t_q[idx] * RF_ + f_q[idx];
        bk[idx] = (NT_ - 1) * RF_ + (NF_ - 1) - (t_k[idx] * RF_ + f_k[idx]);
    }
    if (idx < TAB_) {
        int it = idx / RF_;
        int jf = idx - it * RF_;
        float dt = (float)(it - (NT_ - 1)) / (float)(NT_ - 1);
        float df = (float)(jf - (NF_ - 1)) / (float)(NF_ - 1);
        float enc[32];
#pragma unroll
        for (int i = 0; i < NFREQ_; i++) {
            float fr = expf(-9.210340371976184f * (float)i / (float)NFREQ_); // ln(10000)
            float at = dt * fr, af = df * fr;
            enc[i]            = sinf(at);
            enc[NFREQ_ + i]   = cosf(at);
            enc[2*NFREQ_ + i] = sinf(af);
            enc[3*NFREQ_ + i] = cosf(af);
        }
#pragma unroll
        for (int hh = 0; hh < H_; hh++) {
            float s = 0.f;
#pragma unroll
            for (int j = 0; j < 32; j++) s += enc[j] * W_rpe[hh * 32 + j];
            table[hh * TAB_ + idx] = (_Float16)s;
        }
    }
}

// ---------------------------------------------------------------------------
// K3: fp16 MFMA GEMM  C = scale * (A @ W^T).  A: [8064][256] fp16 row-major,
// W: [256][256] fp32 (converted while staging into LDS in B-fragment order).
// Block 64x64, 4 waves (wave w: rows w*16), K=256 = 8 chunks, 32 MFMAs/wave.
// MODE 0: fp16 head-split  out[bh][q][dk]      (Q with scale, K)
// MODE 1: fp16 transposed  out[bh][dk][q]      (V -> Vt for PV A-fragments)
// MODE 2: fp32 row-major   out[m][256]         (final W_o)
// ---------------------------------------------------------------------------
template <int MODE>
__global__ __launch_bounds__(256, 4) void gemm16(const _Float16* __restrict__ A,
                                                 const float* __restrict__ W,
                                                 void* __restrict__ outp, float scale)
{
    __shared__ __align__(16) _Float16 fw[8 * 4 * 64 * 8];   // 32 KB, fragment-ordered
    const int tid = threadIdx.x;
    const int w = tid >> 6, lane = tid & 63, quad = lane >> 4, l15 = lane & 15;
    const int m0 = blockIdx.x * 64, n0 = blockIdx.y * 64;
#pragma unroll
    for (int p = 0; p < 8; p++) {
        int g = p * 256 + tid;
        int ch = g >> 8, rem = g & 255, nt = rem >> 6, L = rem & 63;
        const float* src = &W[(size_t)(n0 + nt * 16 + (L & 15)) * D_ + ch * 32 + ((L >> 4) & 3) * 8];
        float4 w0 = *(const float4*)src;
        float4 w1 = *(const float4*)(src + 4);
        half8_t hv = { (_Float16)w0.x, (_Float16)w0.y, (_Float16)w0.z, (_Float16)w0.w,
                       (_Float16)w1.x, (_Float16)w1.y, (_Float16)w1.z, (_Float16)w1.w };
        *(half8_t*)&fw[g * 8] = hv;
    }
    __syncthreads();

    f32x4 acc[4] = { {0,0,0,0}, {0,0,0,0}, {0,0,0,0}, {0,0,0,0} };
    const _Float16* Arow = &A[(size_t)(m0 + w * 16 + l15) * D_];
#pragma unroll
    for (int ch = 0; ch < 8; ch++) {
        half8_t af = *(const half8_t*)&Arow[ch * 32 + quad * 8];
#pragma unroll
        for (int nt = 0; nt < 4; nt++) {
            half8_t bf = *(const half8_t*)&fw[((ch * 4 + nt) * 64 + lane) * 8];
            acc[nt] = __builtin_amdgcn_mfma_f32_16x16x32_f16(af, bf, acc[nt], 0, 0, 0);
        }
    }
    // C/D layout: col n = n0+nt*16+l15, rows m = m0+w*16+quad*4+r
    const int mbase = m0 + w * 16 + quad * 4;
    if (MODE == 0) {
        _Float16* out = (_Float16*)outp;
#pragma unroll
        for (int nt = 0; nt < 4; nt++) {
            int n = n0 + nt * 16 + l15;
            int hh = n >> 5, d = n & 31;
#pragma unroll
            for (int r = 0; r < 4; r++) {
                int m = mbase + r, bb = m / N_, q = m - bb * N_;
                out[(((size_t)bb * H_ + hh) * N_ + q) * DK_ + d] = (_Float16)(acc[nt][r] * scale);
            }
        }
    } else if (MODE == 1) {
        _Float16* out = (_Float16*)outp;
        int bb = mbase / N_, q = mbase - bb * N_;   // 4-row group never crosses b (1008%4==0)
#pragma unroll
        for (int nt = 0; nt < 4; nt++) {
            int n = n0 + nt * 16 + l15;
            int hh = n >> 5, d = n & 31;
            half4_t o = { (_Float16)acc[nt][0], (_Float16)acc[nt][1],
                          (_Float16)acc[nt][2], (_Float16)acc[nt][3] };
            *(half4_t*)&out[(((size_t)bb * H_ + hh) * DK_ + d) * N_ + q] = o;
        }
    } else {
        float* out = (float*)outp;
#pragma unroll
        for (int nt = 0; nt < 4; nt++) {
            int n = n0 + nt * 16 + l15;
#pragma unroll
            for (int r = 0; r < 4; r++) {
                out[(size_t)(mbase + r) * D_ + n] = acc[nt][r];
            }
        }
    }
}

// ---------------------------------------------------------------------------
// K4: MFMA flash attention with RPE bias.
// grid (16 qtiles, 64 bh), 256 thr / 4 waves; wave w owns 16 q-rows.
// S^T = K·Q^T per 16x16x32 MFMA (one per tile: DK=32). C-layout: lane holds
// col q = lane&15 (softmax state is scalar/lane), rows k = mt*16+quad*4+r.
// P^T -> B-operand via per-wave-private LDS round trip (no barrier).
// O^T = V^T·P^T accumulated in C-layout (rows d, col q).
// K/V fragments staged double-buffered in fragment order: 1 barrier/tile.
// ---------------------------------------------------------------------------
__global__ __launch_bounds__(256, 4) void attn16(const _Float16* __restrict__ Qh,
    const _Float16* __restrict__ Kh, const _Float16* __restrict__ Vt,
    const _Float16* __restrict__ tabh, const int* __restrict__ aq,
    const int* __restrict__ bk, _Float16* __restrict__ AO)
{
    __shared__ __align__(16) _Float16 tab_s[TAB_ + 3];  // 7.7 KB per-head bias table
    __shared__ __align__(16) int      bk_s[N_];         // 4.0 KB
    __shared__ __align__(16) _Float16 fk[2][2048];      // 8 KB  K B-op... A-frags (dbuf)
    __shared__ __align__(16) _Float16 fv[2][2048];      // 8 KB  V^T A-frags (dbuf)
    __shared__ __align__(16) _Float16 plds[4][16][72];  // 9 KB  per-wave P transpose

    const int tid = threadIdx.x;
    const int w = tid >> 6, lane = tid & 63, quad = lane >> 4, l15 = lane & 15;
    const int bh = blockIdx.y;
    const int q0 = blockIdx.x * 64;
    const int b = bh >> 3, hh = bh & 7;

    const _Float16* Kb = Kh + (size_t)bh * N_ * DK_;
    const _Float16* Vb = Vt + (size_t)bh * DK_ * N_;
    const _Float16* th = tabh + (size_t)hh * TAB_;
    for (int i = tid; i < TAB_; i += 256) tab_s[i] = th[i];
    for (int i = tid; i < N_; i += 256)  bk_s[i] = bk[i];

    const int qg = q0 + w * 16 + l15;
    const int qc = qg < N_ ? qg : N_ - 1;               // block 15 wave 3: compute-only
    half8_t qf = *(const half8_t*)&Qh[((size_t)bh * N_ + qc) * DK_ + quad * 8];
    const int aql = aq[qc];

    float m_run = -1e30f, l_run = 0.f;
    f32x4 O[2] = { {0,0,0,0}, {0,0,0,0} };

    // stage tile 0 (no clamps needed: k<64)
    {
        int krow = ((tid >> 6) & 3) * 16 + (tid & 15);
        *(half8_t*)&fk[0][tid * 8] = *(const half8_t*)&Kb[(size_t)krow * DK_ + ((tid >> 4) & 3) * 8];
        int vrow = ((tid >> 6) & 1) * 16 + (tid & 15);
        int vcol = (tid >> 7) * 32 + ((tid >> 4) & 3) * 8;
        *(half8_t*)&fv[0][tid * 8] = *(const half8_t*)&Vb[(size_t)vrow * N_ + vcol];
    }
    __syncthreads();

    for (int kt = 0; kt < 16; kt++) {
        const int cb = kt & 1;
        const int k0 = kt * 64;
        if (kt < 15) {   // prefetch next tile into other buffer
            int nk0 = k0 + 64;
            int krow = nk0 + ((tid >> 6) & 3) * 16 + (tid & 15);
            if (krow > N_ - 1) krow = N_ - 1;           // clamped rows get masked later
            *(half8_t*)&fk[cb ^ 1][tid * 8] =
                *(const half8_t*)&Kb[(size_t)krow * DK_ + ((tid >> 4) & 3) * 8];
            int vrow = ((tid >> 6) & 1) * 16 + (tid & 15);
            int vcol = nk0 + (tid >> 7) * 32 + ((tid >> 4) & 3) * 8;
            if (vcol > N_ - 8) vcol = N_ - 8;           // keep 16B alignment (1000%8==0)
            *(half8_t*)&fv[cb ^ 1][tid * 8] =
                *(const half8_t*)&Vb[(size_t)vrow * N_ + vcol];
        }
        // S^T tiles
        f32x4 S[4];
#pragma unroll
        for (int mt = 0; mt < 4; mt++) {
            half8_t kf = *(const half8_t*)&fk[cb][(mt * 64 + lane) * 8];
            f32x4 z = {0.f, 0.f, 0.f, 0.f};
            S[mt] = __builtin_amdgcn_mfma_f32_16x16x32_f16(kf, qf, z, 0, 0, 0);
        }
        // bias + tail mask, tile max
        float tmax = -1e30f;
#pragma unroll
        for (int mt = 0; mt < 4; mt++) {
#pragma unroll
            for (int r = 0; r < 4; r++) {
                int kg = k0 + mt * 16 + quad * 4 + r;
                float s;
                if (kg < N_) s = S[mt][r] + (float)tab_s[aql + bk_s[kg]];
                else         s = -1e30f;
                S[mt][r] = s;
                tmax = fmaxf(tmax, s);
            }
        }
        tmax = fmaxf(tmax, __shfl_xor(tmax, 16, 64));
        tmax = fmaxf(tmax, __shfl_xor(tmax, 32, 64));
        float mnew = fmaxf(m_run, tmax);
        float alpha = __expf(m_run - mnew);
        m_run = mnew;
        float tsum = 0.f;
#pragma unroll
        for (int mt = 0; mt < 4; mt++) {
            float p0 = __expf(S[mt][0] - mnew);
            float p1 = __expf(S[mt][1] - mnew);
            float p2 = __expf(S[mt][2] - mnew);
            float p3 = __expf(S[mt][3] - mnew);
            tsum += (p0 + p1) + (p2 + p3);
            half4_t ph = { (_Float16)p0, (_Float16)p1, (_Float16)p2, (_Float16)p3 };
            *(half4_t*)&plds[w][l15][mt * 16 + quad * 4] = ph;   // P^T[k][q], row=own q
        }
        tsum += __shfl_xor(tsum, 16, 64);
        tsum += __shfl_xor(tsum, 32, 64);
        l_run = l_run * alpha + tsum;
        O[0] = O[0] * alpha;
        O[1] = O[1] * alpha;
        // PV: O^T[d][q] += V^T · P^T  (plds read is same-wave, lgkmcnt-ordered)
#pragma unroll
        for (int mt2 = 0; mt2 < 2; mt2++) {
#pragma unroll
            for (int c = 0; c < 2; c++) {
                half8_t pf = *(const half8_t*)&plds[w][l15][c * 32 + quad * 8];
                half8_t vf = *(const half8_t*)&fv[cb][((c * 2 + mt2) * 64 + lane) * 8];
                O[mt2] = __builtin_amdgcn_mfma_f32_16x16x32_f16(vf, pf, O[mt2], 0, 0, 0);
            }
        }
        __syncthreads();   // staged buffer ready / compute done before overwrite
    }

    if (qg < N_) {
        float inv = 1.f / l_run;
#pragma unroll
        for (int mt2 = 0; mt2 < 2; mt2++) {
            half4_t o = { (_Float16)(O[mt2][0] * inv), (_Float16)(O[mt2][1] * inv),
                          (_Float16)(O[mt2][2] * inv), (_Float16)(O[mt2][3] * inv) };
            *(half4_t*)&AO[((size_t)b * N_ + qg) * D_ + hh * DK_ + mt2 * 16 + quad * 4] = o;
        }
    }
}

// ---------------------------------------------------------------------------
extern "C" void kernel_launch(void* const* d_in, const int* in_sizes, int n_in,
                              void* d_out, int out_size, void* d_ws, size_t ws_size,
                              hipStream_t stream)
{
    const float* q_tokens = (const float*)d_in[0];
    const float* k_tokens = (const float*)d_in[1];
    const float* v_tokens = (const float*)d_in[2];
    const int*   t_q      = (const int*)d_in[3];
    const int*   f_q      = (const int*)d_in[4];
    const int*   t_k      = (const int*)d_in[5];
    const int*   f_k      = (const int*)d_in[6];
    // d_in[7]=N_t, d_in[8]=N_f hardcoded
    const float* W_q   = (const float*)d_in[9];
    const float* W_k   = (const float*)d_in[10];
    const float* W_v   = (const float*)d_in[11];
    const float* W_o   = (const float*)d_in[12];
    const float* W_rpe = (const float*)d_in[13];

    // ws layout (fp16 elements unless noted): ~29 MB
    _Float16* ws   = (_Float16*)d_ws;
    _Float16* Qtok = ws;                 // BND_
    _Float16* Ktok = Qtok + BND_;        // BND_
    _Float16* Vtok = Ktok + BND_;        // BND_
    _Float16* Qhp  = Vtok + BND_;        // BND_  [bh][q][dk]
    _Float16* Khp  = Qhp + BND_;         // BND_  [bh][k][dk]
    _Float16* Vth  = Khp + BND_;         // BND_  [bh][dk][k]
    _Float16* AO   = Vth + BND_;         // BND_  [b][q][256]
    _Float16* tabh = AO + BND_;          // 8*3861 (pad to 30896)
    int* aq = (int*)(tabh + 30896);      // N_
    int* bk = aq + 1024;                 // N_

    cvt_tokens<<<dim3(2016, 3), 256, 0, stream>>>(q_tokens, k_tokens, v_tokens,
                                                  Qtok, Ktok, Vtok);
    rpe_table_kernel<<<dim3(16), dim3(256), 0, stream>>>(W_rpe, t_q, f_q, t_k, f_k,
                                                         tabh, aq, bk);
    const float qscale = 0.17677669529663687f;  // 1/sqrt(32)
    gemm16<0><<<dim3(126, 4), dim3(256), 0, stream>>>(Qtok, W_q, Qhp, qscale);
    gemm16<0><<<dim3(126, 4), dim3(256), 0, stream>>>(Ktok, W_k, Khp, 1.0f);
    gemm16<1><<<dim3(126, 4), dim3(256), 0, stream>>>(Vtok, W_v, Vth, 1.0f);

    attn16<<<dim3(16, 64), dim3(256), 0, stream>>>(Qhp, Khp, Vth, tabh, aq, bk, AO);

    gemm16<2><<<dim3(126, 4), dim3(256), 0, stream>>>(AO, W_o, d_out, 1.0f);
}

// Round 3
// 169.466 us; speedup vs baseline: 3.2153x; 1.0354x over previous
//
#include <hip/hip_runtime.h>

// Problem constants (B=8, N_t=14, N_f=72, d_model=256, h=8, d_rpe=32)
#define B_    8
#define N_    1008
#define D_    256
#define H_    8
#define DK_   32
#define DA_   64           // augmented head dim: 32 qk + 32 rpe (rank-32 bias factorization)
#define BND_  (B_*N_*D_)

typedef _Float16 half8_t __attribute__((ext_vector_type(8)));
typedef _Float16 half4_t __attribute__((ext_vector_type(4)));
typedef float    f32x4   __attribute__((ext_vector_type(4)));

// ---------------------------------------------------------------------------
// K1: prep — rank-32 RPE factorization.
//   bias_h(q,k) = sum_i Ws*sin(dt*w)+Wc*cos(dt*w) + (f part)
//               = U_q^h . V_k   (angle addition; exact identity)
// U rows -> Qa[bh][q][32:64] (8 b-copies), V rows -> Ka[bh][k][32:64] (64 copies).
// ---------------------------------------------------------------------------
__global__ void prep_kernel(const int* __restrict__ t_q, const int* __restrict__ f_q,
                            const int* __restrict__ t_k, const int* __restrict__ f_k,
                            const float* __restrict__ W_rpe,
                            _Float16* __restrict__ Qa, _Float16* __restrict__ Ka)
{
    const float FR[8] = {1.f, 0.31622776601683794f, 0.1f, 0.03162277660168379f,
                         0.01f, 0.0031622776601683794f, 0.001f, 0.00031622776601683794f};
    int id = blockIdx.x * 256 + threadIdx.x;
    if (id < N_ * H_) {
        int q = id >> 3, h = id & 7;
        float tq = (float)t_q[q] * (1.f / 13.f);
        float fq = (float)f_q[q] * (1.f / 71.f);
        const float* Wh = W_rpe + h * 32;
        half8_t u0, u1, u2, u3;
#pragma unroll
        for (int i = 0; i < 8; i++) {
            float sa = sinf(tq * FR[i]), ca = cosf(tq * FR[i]);
            float sb = sinf(fq * FR[i]), cb = cosf(fq * FR[i]);
            u0[i] = (_Float16)(Wh[i] * sa + Wh[8 + i] * ca);
            u1[i] = (_Float16)(Wh[8 + i] * sa - Wh[i] * ca);
            u2[i] = (_Float16)(Wh[16 + i] * sb + Wh[24 + i] * cb);
            u3[i] = (_Float16)(Wh[24 + i] * sb - Wh[16 + i] * cb);
        }
#pragma unroll
        for (int b = 0; b < 8; b++) {
            _Float16* dst = &Qa[(((size_t)(b * 8 + h)) * N_ + q) * DA_ + 32];
            *(half8_t*)(dst + 0) = u0;  *(half8_t*)(dst + 8) = u1;
            *(half8_t*)(dst + 16) = u2; *(half8_t*)(dst + 24) = u3;
        }
    } else if (id < N_ * H_ + N_ * 64) {
        int id2 = id - N_ * H_;
        int k = id2 >> 6, bh = id2 & 63;
        float tk = (float)t_k[k] * (1.f / 13.f);
        float fk = (float)f_k[k] * (1.f / 71.f);
        half8_t v0, v1, v2, v3;
#pragma unroll
        for (int i = 0; i < 8; i++) {
            v0[i] = (_Float16)cosf(tk * FR[i]);
            v1[i] = (_Float16)sinf(tk * FR[i]);
            v2[i] = (_Float16)cosf(fk * FR[i]);
            v3[i] = (_Float16)sinf(fk * FR[i]);
        }
        _Float16* dst = &Ka[(((size_t)bh) * N_ + k) * DA_ + 32];
        *(half8_t*)(dst + 0) = v0;  *(half8_t*)(dst + 8) = v1;
        *(half8_t*)(dst + 16) = v2; *(half8_t*)(dst + 24) = v3;
    }
}

// ---------------------------------------------------------------------------
// K2: fused QKV projection, fp16 MFMA, fp32 inputs converted in-register.
// Block 128x128 tile (grid 63x2x3, z selects Q/K/V). W staged fp32->fp16 into
// LDS in B-fragment order; A rows read as float4 pairs -> half8 A-fragments.
// z=0: Qa[bh][q][0:32] * 1/sqrt(32); z=1: Ka[bh][k][0:32]; z=2: Vt[bh][d][k].
// ---------------------------------------------------------------------------
__global__ __launch_bounds__(256, 2) void qkv_gemm(
    const float* __restrict__ q_tok, const float* __restrict__ k_tok,
    const float* __restrict__ v_tok, const float* __restrict__ Wq,
    const float* __restrict__ Wk, const float* __restrict__ Wv,
    _Float16* __restrict__ Qa, _Float16* __restrict__ Ka, _Float16* __restrict__ Vt)
{
    __shared__ __align__(16) _Float16 fw[8 * 8 * 64 * 8];   // 64 KB
    const int tid = threadIdx.x;
    const int lane = tid & 63, w = tid >> 6, quad = lane >> 4, l15 = lane & 15;
    const int z = blockIdx.z;
    const int m0 = blockIdx.x * 128, n0 = blockIdx.y * 128;
    const float* A = (z == 0) ? q_tok : (z == 1) ? k_tok : v_tok;
    const float* W = (z == 0) ? Wq : (z == 1) ? Wk : Wv;

#pragma unroll
    for (int p = 0; p < 16; p++) {
        int g = p * 256 + tid;
        int ch = g >> 9, rem = g & 511, nt = rem >> 6, L = rem & 63;
        const float* src = &W[(size_t)(n0 + nt * 16 + (L & 15)) * D_ + ch * 32 + ((L >> 4) & 3) * 8];
        float4 w0 = *(const float4*)src;
        float4 w1 = *(const float4*)(src + 4);
        half8_t hv = {(_Float16)w0.x, (_Float16)w0.y, (_Float16)w0.z, (_Float16)w0.w,
                      (_Float16)w1.x, (_Float16)w1.y, (_Float16)w1.z, (_Float16)w1.w};
        *(half8_t*)&fw[g * 8] = hv;
    }
    __syncthreads();

    f32x4 acc[2][8] = {};
    const float* Ar0 = &A[(size_t)(m0 + w * 16 + l15) * D_];
    const float* Ar1 = Ar0 + (size_t)64 * D_;
#pragma unroll
    for (int ch = 0; ch < 8; ch++) {
        float4 a00 = *(const float4*)&Ar0[ch * 32 + quad * 8];
        float4 a01 = *(const float4*)&Ar0[ch * 32 + quad * 8 + 4];
        float4 a10 = *(const float4*)&Ar1[ch * 32 + quad * 8];
        float4 a11 = *(const float4*)&Ar1[ch * 32 + quad * 8 + 4];
        half8_t af0 = {(_Float16)a00.x, (_Float16)a00.y, (_Float16)a00.z, (_Float16)a00.w,
                       (_Float16)a01.x, (_Float16)a01.y, (_Float16)a01.z, (_Float16)a01.w};
        half8_t af1 = {(_Float16)a10.x, (_Float16)a10.y, (_Float16)a10.z, (_Float16)a10.w,
                       (_Float16)a11.x, (_Float16)a11.y, (_Float16)a11.z, (_Float16)a11.w};
#pragma unroll
        for (int nt = 0; nt < 8; nt++) {
            half8_t bf = *(const half8_t*)&fw[((ch * 8 + nt) * 64 + lane) * 8];
            acc[0][nt] = __builtin_amdgcn_mfma_f32_16x16x32_f16(af0, bf, acc[0][nt], 0, 0, 0);
            acc[1][nt] = __builtin_amdgcn_mfma_f32_16x16x32_f16(af1, bf, acc[1][nt], 0, 0, 0);
        }
    }
    const float scale = (z == 0) ? 0.17677669529663687f : 1.0f;   // 1/sqrt(32)
#pragma unroll
    for (int mt = 0; mt < 2; mt++) {
        int mbase = m0 + mt * 64 + w * 16 + quad * 4;
        int b = mbase / N_;
        int q = mbase - b * N_;          // 4-row group never crosses b (1008%4==0)
        if (z < 2) {
            _Float16* out = (z == 0) ? Qa : Ka;
#pragma unroll
            for (int nt = 0; nt < 8; nt++) {
                int n = n0 + nt * 16 + l15;
                int hh = n >> 5, d = n & 31;
                _Float16* dst = &out[(((size_t)(b * 8 + hh)) * N_ + q) * DA_ + d];
#pragma unroll
                for (int r = 0; r < 4; r++)
                    dst[(size_t)r * DA_] = (_Float16)(acc[mt][nt][r] * scale);
            }
        } else {
#pragma unroll
            for (int nt = 0; nt < 8; nt++) {
                int n = n0 + nt * 16 + l15;
                int hh = n >> 5, d = n & 31;
                half4_t o = {(_Float16)acc[mt][nt][0], (_Float16)acc[mt][nt][1],
                             (_Float16)acc[mt][nt][2], (_Float16)acc[mt][nt][3]};
                *(half4_t*)&Vt[(((size_t)(b * 8 + hh)) * DK_ + d) * N_ + q] = o;
            }
        }
    }
}

// ---------------------------------------------------------------------------
// K3: MFMA flash attention, dk=64 augmented (scores+bias in one MFMA chain).
// grid (8 qtiles x 128, 64 bh), 4 waves; wave owns 32 q (2 groups of 16).
// S^T = K~ . Q~^T (2 chained MFMAs per 16k tile). No table/gather at all.
// P^T -> B-operand via per-wave LDS round trip; O^T = V^T . P^T.
// K~/V^T staged double-buffered in fragment order; 1 barrier/tile.
// ---------------------------------------------------------------------------
__global__ __launch_bounds__(256, 2) void attn(const _Float16* __restrict__ Qa,
    const _Float16* __restrict__ Ka, const _Float16* __restrict__ Vt,
    _Float16* __restrict__ AO)
{
    __shared__ __align__(16) _Float16 fk[2][4096];      // 16 KB K~ A-frags (dbuf)
    __shared__ __align__(16) _Float16 fv[2][2048];      // 8 KB  V^T A-frags (dbuf)
    __shared__ __align__(16) _Float16 plds[4][2][16][72]; // 18 KB per-wave P transpose

    const int tid = threadIdx.x;
    const int lane = tid & 63, w = tid >> 6, quad = lane >> 4, l15 = lane & 15;
    const int bh = blockIdx.y, q0 = blockIdx.x * 128;
    const int b = bh >> 3, hh = bh & 7;
    const _Float16* Kb = Ka + (size_t)bh * N_ * DA_;
    const _Float16* Vb = Vt + (size_t)bh * DK_ * N_;

    // staging decomposition of tid
    const int s_l15 = tid & 15, s_quad = (tid >> 4) & 3;
    const int s_mt = tid >> 6;           // fk k-row group 0..3
    const int s_c = tid >> 7;            // fv k-col group 0..1
    const int s_mt2 = (tid >> 6) & 1;    // fv d-row group 0..1

    half8_t qf[2][2];
    int qg[2];
#pragma unroll
    for (int g = 0; g < 2; g++) {
        qg[g] = q0 + w * 32 + g * 16 + l15;
        int qc = qg[g] < N_ ? qg[g] : N_ - 1;    // clamped lanes compute, don't store
        const _Float16* Qrow = &Qa[((size_t)bh * N_ + qc) * DA_];
        qf[g][0] = *(const half8_t*)&Qrow[quad * 8];
        qf[g][1] = *(const half8_t*)&Qrow[32 + quad * 8];
    }

    float m_run[2] = {-1e30f, -1e30f}, l_run[2] = {0.f, 0.f};
    f32x4 O[2][2] = {};

    {   // stage tile 0
        int krow = s_mt * 16 + s_l15;
        *(half8_t*)&fk[0][((s_mt * 2 + 0) * 64 + lane) * 8] =
            *(const half8_t*)&Kb[(size_t)krow * DA_ + s_quad * 8];
        *(half8_t*)&fk[0][((s_mt * 2 + 1) * 64 + lane) * 8] =
            *(const half8_t*)&Kb[(size_t)krow * DA_ + 32 + s_quad * 8];
        int vrow = s_mt2 * 16 + s_l15;
        int vcol = s_c * 32 + s_quad * 8;
        *(half8_t*)&fv[0][tid * 8] = *(const half8_t*)&Vb[(size_t)vrow * N_ + vcol];
    }
    __syncthreads();

    for (int kt = 0; kt < 16; kt++) {
        const int cb = kt & 1;
        if (kt < 15) {   // prefetch next tile
            int k0n = (kt + 1) * 64;
            int krow = k0n + s_mt * 16 + s_l15;
            if (krow > N_ - 1) krow = N_ - 1;      // dup rows masked via S[3] at kt=15
            *(half8_t*)&fk[cb ^ 1][((s_mt * 2 + 0) * 64 + lane) * 8] =
                *(const half8_t*)&Kb[(size_t)krow * DA_ + s_quad * 8];
            *(half8_t*)&fk[cb ^ 1][((s_mt * 2 + 1) * 64 + lane) * 8] =
                *(const half8_t*)&Kb[(size_t)krow * DA_ + 32 + s_quad * 8];
            int vrow = s_mt2 * 16 + s_l15;
            int vcol = k0n + s_c * 32 + s_quad * 8;
            if (vcol > N_ - 8) vcol = N_ - 8;      // aligned dup, P=0 there
            *(half8_t*)&fv[cb ^ 1][tid * 8] = *(const half8_t*)&Vb[(size_t)vrow * N_ + vcol];
        }
        half8_t kf[4][2], vf[4];
#pragma unroll
        for (int mt = 0; mt < 4; mt++) {
            kf[mt][0] = *(const half8_t*)&fk[cb][((mt * 2 + 0) * 64 + lane) * 8];
            kf[mt][1] = *(const half8_t*)&fk[cb][((mt * 2 + 1) * 64 + lane) * 8];
        }
#pragma unroll
        for (int f2 = 0; f2 < 4; f2++)
            vf[f2] = *(const half8_t*)&fv[cb][(f2 * 64 + lane) * 8];

#pragma unroll
        for (int g = 0; g < 2; g++) {
            f32x4 S[4];
#pragma unroll
            for (int mt = 0; mt < 4; mt++) {
                f32x4 zz = {0.f, 0.f, 0.f, 0.f};
                zz = __builtin_amdgcn_mfma_f32_16x16x32_f16(kf[mt][0], qf[g][0], zz, 0, 0, 0);
                S[mt] = __builtin_amdgcn_mfma_f32_16x16x32_f16(kf[mt][1], qf[g][1], zz, 0, 0, 0);
            }
            if (kt == 15)   // k 1008..1023 live entirely in mt=3 (1008-960=48)
                S[3] = (f32x4){-1e30f, -1e30f, -1e30f, -1e30f};
            float tmax = -1e30f;
#pragma unroll
            for (int mt = 0; mt < 4; mt++)
#pragma unroll
                for (int r = 0; r < 4; r++) tmax = fmaxf(tmax, S[mt][r]);
            tmax = fmaxf(tmax, __shfl_xor(tmax, 16, 64));
            tmax = fmaxf(tmax, __shfl_xor(tmax, 32, 64));
            float mnew = fmaxf(m_run[g], tmax);
            float alpha = __expf(m_run[g] - mnew);
            m_run[g] = mnew;
            float tsum = 0.f;
#pragma unroll
            for (int mt = 0; mt < 4; mt++) {
                float p0 = __expf(S[mt][0] - mnew), p1 = __expf(S[mt][1] - mnew);
                float p2 = __expf(S[mt][2] - mnew), p3 = __expf(S[mt][3] - mnew);
                tsum += (p0 + p1) + (p2 + p3);
                half4_t ph = {(_Float16)p0, (_Float16)p1, (_Float16)p2, (_Float16)p3};
                *(half4_t*)&plds[w][g][l15][mt * 16 + quad * 4] = ph;  // P^T[q][k]
            }
            tsum += __shfl_xor(tsum, 16, 64);
            tsum += __shfl_xor(tsum, 32, 64);
            l_run[g] = l_run[g] * alpha + tsum;
            O[g][0] = O[g][0] * alpha;
            O[g][1] = O[g][1] * alpha;
        }
        // PV: O^T[d][q] += V^T . P^T   (same-wave LDS ordering, no barrier)
#pragma unroll
        for (int g = 0; g < 2; g++) {
#pragma unroll
            for (int c = 0; c < 2; c++) {
                half8_t pf = *(const half8_t*)&plds[w][g][l15][c * 32 + quad * 8];
                O[g][0] = __builtin_amdgcn_mfma_f32_16x16x32_f16(vf[c * 2 + 0], pf, O[g][0], 0, 0, 0);
                O[g][1] = __builtin_amdgcn_mfma_f32_16x16x32_f16(vf[c * 2 + 1], pf, O[g][1], 0, 0, 0);
            }
        }
        __syncthreads();   // dbuf: staged tile ready / reads done before overwrite
    }
#pragma unroll
    for (int g = 0; g < 2; g++) {
        if (qg[g] < N_) {
            float inv = 1.f / l_run[g];
#pragma unroll
            for (int mt2 = 0; mt2 < 2; mt2++) {
                half4_t o = {(_Float16)(O[g][mt2][0] * inv), (_Float16)(O[g][mt2][1] * inv),
                             (_Float16)(O[g][mt2][2] * inv), (_Float16)(O[g][mt2][3] * inv)};
                *(half4_t*)&AO[((size_t)b * N_ + qg[g]) * D_ + hh * DK_ + mt2 * 16 + quad * 4] = o;
            }
        }
    }
}

// ---------------------------------------------------------------------------
// K4: output projection  out = AO @ W_o^T, fp16 A, fp32 out. 128x128 tiles.
// ---------------------------------------------------------------------------
__global__ __launch_bounds__(256, 2) void out_gemm(const _Float16* __restrict__ A,
    const float* __restrict__ W, float* __restrict__ out)
{
    __shared__ __align__(16) _Float16 fw[8 * 8 * 64 * 8];   // 64 KB
    const int tid = threadIdx.x;
    const int lane = tid & 63, w = tid >> 6, quad = lane >> 4, l15 = lane & 15;
    const int m0 = blockIdx.x * 128, n0 = blockIdx.y * 128;

#pragma unroll
    for (int p = 0; p < 16; p++) {
        int g = p * 256 + tid;
        int ch = g >> 9, rem = g & 511, nt = rem >> 6, L = rem & 63;
        const float* src = &W[(size_t)(n0 + nt * 16 + (L & 15)) * D_ + ch * 32 + ((L >> 4) & 3) * 8];
        float4 w0 = *(const float4*)src;
        float4 w1 = *(const float4*)(src + 4);
        half8_t hv = {(_Float16)w0.x, (_Float16)w0.y, (_Float16)w0.z, (_Float16)w0.w,
                      (_Float16)w1.x, (_Float16)w1.y, (_Float16)w1.z, (_Float16)w1.w};
        *(half8_t*)&fw[g * 8] = hv;
    }
    __syncthreads();

    f32x4 acc[2][8] = {};
    const _Float16* Ar0 = &A[(size_t)(m0 + w * 16 + l15) * D_];
    const _Float16* Ar1 = Ar0 + (size_t)64 * D_;
#pragma unroll
    for (int ch = 0; ch < 8; ch++) {
        half8_t af0 = *(const half8_t*)&Ar0[ch * 32 + quad * 8];
        half8_t af1 = *(const half8_t*)&Ar1[ch * 32 + quad * 8];
#pragma unroll
        for (int nt = 0; nt < 8; nt++) {
            half8_t bf = *(const half8_t*)&fw[((ch * 8 + nt) * 64 + lane) * 8];
            acc[0][nt] = __builtin_amdgcn_mfma_f32_16x16x32_f16(af0, bf, acc[0][nt], 0, 0, 0);
            acc[1][nt] = __builtin_amdgcn_mfma_f32_16x16x32_f16(af1, bf, acc[1][nt], 0, 0, 0);
        }
    }
#pragma unroll
    for (int mt = 0; mt < 2; mt++) {
        int mbase = m0 + mt * 64 + w * 16 + quad * 4;
#pragma unroll
        for (int nt = 0; nt < 8; nt++) {
            int n = n0 + nt * 16 + l15;
#pragma unroll
            for (int r = 0; r < 4; r++)
                out[(size_t)(mbase + r) * D_ + n] = acc[mt][nt][r];
        }
    }
}

// ---------------------------------------------------------------------------
extern "C" void kernel_launch(void* const* d_in, const int* in_sizes, int n_in,
                              void* d_out, int out_size, void* d_ws, size_t ws_size,
                              hipStream_t stream)
{
    const float* q_tokens = (const float*)d_in[0];
    const float* k_tokens = (const float*)d_in[1];
    const float* v_tokens = (const float*)d_in[2];
    const int*   t_q      = (const int*)d_in[3];
    const int*   f_q      = (const int*)d_in[4];
    const int*   t_k      = (const int*)d_in[5];
    const int*   f_k      = (const int*)d_in[6];
    // d_in[7]=N_t, d_in[8]=N_f hardcoded
    const float* W_q   = (const float*)d_in[9];
    const float* W_k   = (const float*)d_in[10];
    const float* W_v   = (const float*)d_in[11];
    const float* W_o   = (const float*)d_in[12];
    const float* W_rpe = (const float*)d_in[13];

    // ws layout (fp16): Qa/Ka [bh][n][64] augmented, Vt [bh][32][n], AO [b][q][256]
    _Float16* ws = (_Float16*)d_ws;
    _Float16* Qa = ws;                       // 64*1008*64 = 4128768
    _Float16* Ka = Qa + (size_t)64 * N_ * DA_;
    _Float16* Vt = Ka + (size_t)64 * N_ * DA_;  // 64*32*1008
    _Float16* AO = Vt + (size_t)64 * DK_ * N_;  // 8064*256

    prep_kernel<<<dim3(284), 256, 0, stream>>>(t_q, f_q, t_k, f_k, W_rpe, Qa, Ka);
    qkv_gemm<<<dim3(63, 2, 3), 256, 0, stream>>>(q_tokens, k_tokens, v_tokens,
                                                 W_q, W_k, W_v, Qa, Ka, Vt);
    attn<<<dim3(8, 64), 256, 0, stream>>>(Qa, Ka, Vt, AO);
    out_gemm<<<dim3(63, 2), 256, 0, stream>>>(AO, W_o, (float*)d_out);
}

// Round 4
// 162.137 us; speedup vs baseline: 3.3607x; 1.0452x over previous
//
#include <hip/hip_runtime.h>

// Problem constants (B=8, N_t=14, N_f=72, d_model=256, h=8, d_rpe=32)
#define B_    8
#define N_    1008
#define D_    256
#define H_    8
#define DK_   32
#define DA_   64           // augmented head dim: 32 qk + 32 rpe (rank-32 bias factorization)
#define BND_  (B_*N_*D_)
#define L2E_  1.4426950408889634f

typedef _Float16 half8_t __attribute__((ext_vector_type(8)));
typedef _Float16 half4_t __attribute__((ext_vector_type(4)));
typedef float    f32x4   __attribute__((ext_vector_type(4)));

#if defined(__has_builtin)
#if __has_builtin(__builtin_amdgcn_exp2f)
#define EXP2(x) __builtin_amdgcn_exp2f(x)
#else
#define EXP2(x) exp2f(x)
#endif
#else
#define EXP2(x) exp2f(x)
#endif

// ---------------------------------------------------------------------------
// K1: prep — rank-32 RPE factorization, base-2 softmax domain.
//   log2e * bias_h(q,k) = U_q^h . V_k   (angle addition; exact identity;
//   log2e folded into U so attention can use v_exp_f32 = 2^x directly)
// U rows -> Qa[bh][q][32:64] (8 b-copies), V rows -> Ka[bh][k][32:64] (64 copies).
// ---------------------------------------------------------------------------
__global__ void prep_kernel(const int* __restrict__ t_q, const int* __restrict__ f_q,
                            const int* __restrict__ t_k, const int* __restrict__ f_k,
                            const float* __restrict__ W_rpe,
                            _Float16* __restrict__ Qa, _Float16* __restrict__ Ka)
{
    const float FR[8] = {1.f, 0.31622776601683794f, 0.1f, 0.03162277660168379f,
                         0.01f, 0.0031622776601683794f, 0.001f, 0.00031622776601683794f};
    int id = blockIdx.x * 256 + threadIdx.x;
    if (id < N_ * H_) {
        int q = id >> 3, h = id & 7;
        float tq = (float)t_q[q] * (1.f / 13.f);
        float fq = (float)f_q[q] * (1.f / 71.f);
        const float* Wh = W_rpe + h * 32;
        half8_t u0, u1, u2, u3;
#pragma unroll
        for (int i = 0; i < 8; i++) {
            float sa = sinf(tq * FR[i]), ca = cosf(tq * FR[i]);
            float sb = sinf(fq * FR[i]), cb = cosf(fq * FR[i]);
            u0[i] = (_Float16)(L2E_ * (Wh[i] * sa + Wh[8 + i] * ca));
            u1[i] = (_Float16)(L2E_ * (Wh[8 + i] * sa - Wh[i] * ca));
            u2[i] = (_Float16)(L2E_ * (Wh[16 + i] * sb + Wh[24 + i] * cb));
            u3[i] = (_Float16)(L2E_ * (Wh[24 + i] * sb - Wh[16 + i] * cb));
        }
#pragma unroll
        for (int b = 0; b < 8; b++) {
            _Float16* dst = &Qa[(((size_t)(b * 8 + h)) * N_ + q) * DA_ + 32];
            *(half8_t*)(dst + 0) = u0;  *(half8_t*)(dst + 8) = u1;
            *(half8_t*)(dst + 16) = u2; *(half8_t*)(dst + 24) = u3;
        }
    } else if (id < N_ * H_ + N_ * 64) {
        int id2 = id - N_ * H_;
        int k = id2 >> 6, bh = id2 & 63;
        float tk = (float)t_k[k] * (1.f / 13.f);
        float fk = (float)f_k[k] * (1.f / 71.f);
        half8_t v0, v1, v2, v3;
#pragma unroll
        for (int i = 0; i < 8; i++) {
            v0[i] = (_Float16)cosf(tk * FR[i]);
            v1[i] = (_Float16)sinf(tk * FR[i]);
            v2[i] = (_Float16)cosf(fk * FR[i]);
            v3[i] = (_Float16)sinf(fk * FR[i]);
        }
        _Float16* dst = &Ka[(((size_t)bh) * N_ + k) * DA_ + 32];
        *(half8_t*)(dst + 0) = v0;  *(half8_t*)(dst + 8) = v1;
        *(half8_t*)(dst + 16) = v2; *(half8_t*)(dst + 24) = v3;
    }
}

// ---------------------------------------------------------------------------
// K2: fused QKV projection, fp16 MFMA, fp32 inputs converted in-register.
// Block 128x128 tile (grid 63x2x3, z selects Q/K/V). W staged fp32->fp16 into
// LDS in B-fragment order; A rows read as float4 pairs -> half8 A-fragments.
// z=0: Qa[bh][q][0:32] * log2e/sqrt(32); z=1: Ka[bh][k][0:32]; z=2: Vt[bh][d][k].
// ---------------------------------------------------------------------------
__global__ __launch_bounds__(256, 2) void qkv_gemm(
    const float* __restrict__ q_tok, const float* __restrict__ k_tok,
    const float* __restrict__ v_tok, const float* __restrict__ Wq,
    const float* __restrict__ Wk, const float* __restrict__ Wv,
    _Float16* __restrict__ Qa, _Float16* __restrict__ Ka, _Float16* __restrict__ Vt)
{
    __shared__ __align__(16) _Float16 fw[8 * 8 * 64 * 8];   // 64 KB
    const int tid = threadIdx.x;
    const int lane = tid & 63, w = tid >> 6, quad = lane >> 4, l15 = lane & 15;
    const int z = blockIdx.z;
    const int m0 = blockIdx.x * 128, n0 = blockIdx.y * 128;
    const float* A = (z == 0) ? q_tok : (z == 1) ? k_tok : v_tok;
    const float* W = (z == 0) ? Wq : (z == 1) ? Wk : Wv;

#pragma unroll
    for (int p = 0; p < 16; p++) {
        int g = p * 256 + tid;
        int ch = g >> 9, rem = g & 511, nt = rem >> 6, L = rem & 63;
        const float* src = &W[(size_t)(n0 + nt * 16 + (L & 15)) * D_ + ch * 32 + ((L >> 4) & 3) * 8];
        float4 w0 = *(const float4*)src;
        float4 w1 = *(const float4*)(src + 4);
        half8_t hv = {(_Float16)w0.x, (_Float16)w0.y, (_Float16)w0.z, (_Float16)w0.w,
                      (_Float16)w1.x, (_Float16)w1.y, (_Float16)w1.z, (_Float16)w1.w};
        *(half8_t*)&fw[g * 8] = hv;
    }
    __syncthreads();

    f32x4 acc[2][8] = {};
    const float* Ar0 = &A[(size_t)(m0 + w * 16 + l15) * D_];
    const float* Ar1 = Ar0 + (size_t)64 * D_;
#pragma unroll
    for (int ch = 0; ch < 8; ch++) {
        float4 a00 = *(const float4*)&Ar0[ch * 32 + quad * 8];
        float4 a01 = *(const float4*)&Ar0[ch * 32 + quad * 8 + 4];
        float4 a10 = *(const float4*)&Ar1[ch * 32 + quad * 8];
        float4 a11 = *(const float4*)&Ar1[ch * 32 + quad * 8 + 4];
        half8_t af0 = {(_Float16)a00.x, (_Float16)a00.y, (_Float16)a00.z, (_Float16)a00.w,
                       (_Float16)a01.x, (_Float16)a01.y, (_Float16)a01.z, (_Float16)a01.w};
        half8_t af1 = {(_Float16)a10.x, (_Float16)a10.y, (_Float16)a10.z, (_Float16)a10.w,
                       (_Float16)a11.x, (_Float16)a11.y, (_Float16)a11.z, (_Float16)a11.w};
#pragma unroll
        for (int nt = 0; nt < 8; nt++) {
            half8_t bf = *(const half8_t*)&fw[((ch * 8 + nt) * 64 + lane) * 8];
            acc[0][nt] = __builtin_amdgcn_mfma_f32_16x16x32_f16(af0, bf, acc[0][nt], 0, 0, 0);
            acc[1][nt] = __builtin_amdgcn_mfma_f32_16x16x32_f16(af1, bf, acc[1][nt], 0, 0, 0);
        }
    }
    // base-2 softmax domain: Q also carries log2e
    const float scale = (z == 0) ? 0.17677669529663687f * L2E_ : 1.0f;
#pragma unroll
    for (int mt = 0; mt < 2; mt++) {
        int mbase = m0 + mt * 64 + w * 16 + quad * 4;
        int b = mbase / N_;
        int q = mbase - b * N_;          // 4-row group never crosses b (1008%4==0)
        if (z < 2) {
            _Float16* out = (z == 0) ? Qa : Ka;
#pragma unroll
            for (int nt = 0; nt < 8; nt++) {
                int n = n0 + nt * 16 + l15;
                int hh = n >> 5, d = n & 31;
                _Float16* dst = &out[(((size_t)(b * 8 + hh)) * N_ + q) * DA_ + d];
#pragma unroll
                for (int r = 0; r < 4; r++)
                    dst[(size_t)r * DA_] = (_Float16)(acc[mt][nt][r] * scale);
            }
        } else {
#pragma unroll
            for (int nt = 0; nt < 8; nt++) {
                int n = n0 + nt * 16 + l15;
                int hh = n >> 5, d = n & 31;
                half4_t o = {(_Float16)acc[mt][nt][0], (_Float16)acc[mt][nt][1],
                             (_Float16)acc[mt][nt][2], (_Float16)acc[mt][nt][3]};
                *(half4_t*)&Vt[(((size_t)(b * 8 + hh)) * DK_ + d) * N_ + q] = o;
            }
        }
    }
}

// ---------------------------------------------------------------------------
// K3: MFMA flash attention, dk=64 augmented (scores+bias in one MFMA chain),
// base-2 online softmax (logits pre-scaled by log2e -> bare v_exp_f32).
// grid (16 qtiles x 64, 64 bh), 4 waves; each wave owns 16 q-rows.
// S^T = K~ . Q~^T; P^T -> B-operand via per-wave LDS round trip; O^T = V^T.P^T.
// LDS 33 KB, __launch_bounds__(256,4) -> 4 blocks/CU for barrier overlap.
// ---------------------------------------------------------------------------
__global__ __launch_bounds__(256, 4) void attn(const _Float16* __restrict__ Qa,
    const _Float16* __restrict__ Ka, const _Float16* __restrict__ Vt,
    _Float16* __restrict__ AO)
{
    __shared__ __align__(16) _Float16 fk[2][4096];      // 16 KB K~ A-frags (dbuf)
    __shared__ __align__(16) _Float16 fv[2][2048];      // 8 KB  V^T A-frags (dbuf)
    __shared__ __align__(16) _Float16 plds[4][16][72];  // 9 KB  per-wave P transpose

    const int tid = threadIdx.x;
    const int lane = tid & 63, w = tid >> 6, quad = lane >> 4, l15 = lane & 15;
    const int bh = blockIdx.y, q0 = blockIdx.x * 64;
    const int b = bh >> 3, hh = bh & 7;
    const _Float16* Kb = Ka + (size_t)bh * N_ * DA_;
    const _Float16* Vb = Vt + (size_t)bh * DK_ * N_;

    // staging decomposition of tid
    const int s_l15 = tid & 15, s_quad = (tid >> 4) & 3;
    const int s_mt = tid >> 6;           // fk k-row group 0..3
    const int s_c = tid >> 7;            // fv k-col group 0..1
    const int s_mt2 = (tid >> 6) & 1;    // fv d-row group 0..1

    const int qg = q0 + w * 16 + l15;
    const int qc = qg < N_ ? qg : N_ - 1;     // clamped lanes compute, don't store
    const _Float16* Qrow = &Qa[((size_t)bh * N_ + qc) * DA_];
    half8_t qf0 = *(const half8_t*)&Qrow[quad * 8];
    half8_t qf1 = *(const half8_t*)&Qrow[32 + quad * 8];

    float m_run = -1e30f, l_run = 0.f;
    f32x4 O[2] = {};

    {   // stage tile 0
        int krow = s_mt * 16 + s_l15;
        *(half8_t*)&fk[0][((s_mt * 2 + 0) * 64 + lane) * 8] =
            *(const half8_t*)&Kb[(size_t)krow * DA_ + s_quad * 8];
        *(half8_t*)&fk[0][((s_mt * 2 + 1) * 64 + lane) * 8] =
            *(const half8_t*)&Kb[(size_t)krow * DA_ + 32 + s_quad * 8];
        int vrow = s_mt2 * 16 + s_l15;
        int vcol = s_c * 32 + s_quad * 8;
        *(half8_t*)&fv[0][tid * 8] = *(const half8_t*)&Vb[(size_t)vrow * N_ + vcol];
    }
    __syncthreads();

    for (int kt = 0; kt < 16; kt++) {
        const int cb = kt & 1;
        if (kt < 15) {   // prefetch next tile into other buffer
            int k0n = (kt + 1) * 64;
            int krow = k0n + s_mt * 16 + s_l15;
            if (krow > N_ - 1) krow = N_ - 1;      // dup rows masked via S[3] at kt=15
            *(half8_t*)&fk[cb ^ 1][((s_mt * 2 + 0) * 64 + lane) * 8] =
                *(const half8_t*)&Kb[(size_t)krow * DA_ + s_quad * 8];
            *(half8_t*)&fk[cb ^ 1][((s_mt * 2 + 1) * 64 + lane) * 8] =
                *(const half8_t*)&Kb[(size_t)krow * DA_ + 32 + s_quad * 8];
            int vrow = s_mt2 * 16 + s_l15;
            int vcol = k0n + s_c * 32 + s_quad * 8;
            if (vcol > N_ - 8) vcol = N_ - 8;      // aligned dup, P=0 there
            *(half8_t*)&fv[cb ^ 1][tid * 8] = *(const half8_t*)&Vb[(size_t)vrow * N_ + vcol];
        }
        f32x4 S[4];
#pragma unroll
        for (int mt = 0; mt < 4; mt++) {
            half8_t kf0 = *(const half8_t*)&fk[cb][((mt * 2 + 0) * 64 + lane) * 8];
            half8_t kf1 = *(const half8_t*)&fk[cb][((mt * 2 + 1) * 64 + lane) * 8];
            f32x4 zz = {0.f, 0.f, 0.f, 0.f};
            zz = __builtin_amdgcn_mfma_f32_16x16x32_f16(kf0, qf0, zz, 0, 0, 0);
            S[mt] = __builtin_amdgcn_mfma_f32_16x16x32_f16(kf1, qf1, zz, 0, 0, 0);
        }
        if (kt == 15)   // k 1008..1023 live entirely in mt=3 (1008-960=48)
            S[3] = (f32x4){-1e30f, -1e30f, -1e30f, -1e30f};
        float tmax = -1e30f;
#pragma unroll
        for (int mt = 0; mt < 4; mt++)
#pragma unroll
            for (int r = 0; r < 4; r++) tmax = fmaxf(tmax, S[mt][r]);
        tmax = fmaxf(tmax, __shfl_xor(tmax, 16, 64));
        tmax = fmaxf(tmax, __shfl_xor(tmax, 32, 64));
        float mnew = fmaxf(m_run, tmax);
        float alpha = EXP2(m_run - mnew);
        m_run = mnew;
        float tsum = 0.f;
#pragma unroll
        for (int mt = 0; mt < 4; mt++) {
            float p0 = EXP2(S[mt][0] - mnew), p1 = EXP2(S[mt][1] - mnew);
            float p2 = EXP2(S[mt][2] - mnew), p3 = EXP2(S[mt][3] - mnew);
            tsum += (p0 + p1) + (p2 + p3);
            half4_t ph = {(_Float16)p0, (_Float16)p1, (_Float16)p2, (_Float16)p3};
            *(half4_t*)&plds[w][l15][mt * 16 + quad * 4] = ph;  // P^T[q][k]
        }
        tsum += __shfl_xor(tsum, 16, 64);
        tsum += __shfl_xor(tsum, 32, 64);
        l_run = l_run * alpha + tsum;
        O[0] = O[0] * alpha;
        O[1] = O[1] * alpha;
        // PV: O^T[d][q] += V^T . P^T   (same-wave LDS ordering, no barrier)
#pragma unroll
        for (int c = 0; c < 2; c++) {
            half8_t pf = *(const half8_t*)&plds[w][l15][c * 32 + quad * 8];
            half8_t vfa = *(const half8_t*)&fv[cb][((c * 2 + 0) * 64 + lane) * 8];
            half8_t vfb = *(const half8_t*)&fv[cb][((c * 2 + 1) * 64 + lane) * 8];
            O[0] = __builtin_amdgcn_mfma_f32_16x16x32_f16(vfa, pf, O[0], 0, 0, 0);
            O[1] = __builtin_amdgcn_mfma_f32_16x16x32_f16(vfb, pf, O[1], 0, 0, 0);
        }
        __syncthreads();   // dbuf: staged tile ready / reads done before overwrite
    }
    if (qg < N_) {
        float inv = 1.f / l_run;
#pragma unroll
        for (int mt2 = 0; mt2 < 2; mt2++) {
            half4_t o = {(_Float16)(O[mt2][0] * inv), (_Float16)(O[mt2][1] * inv),
                         (_Float16)(O[mt2][2] * inv), (_Float16)(O[mt2][3] * inv)};
            *(half4_t*)&AO[((size_t)b * N_ + qg) * D_ + hh * DK_ + mt2 * 16 + quad * 4] = o;
        }
    }
}

// ---------------------------------------------------------------------------
// K4: output projection  out = AO @ W_o^T, fp16 A, fp32 out. 128x128 tiles.
// ---------------------------------------------------------------------------
__global__ __launch_bounds__(256, 2) void out_gemm(const _Float16* __restrict__ A,
    const float* __restrict__ W, float* __restrict__ out)
{
    __shared__ __align__(16) _Float16 fw[8 * 8 * 64 * 8];   // 64 KB
    const int tid = threadIdx.x;
    const int lane = tid & 63, w = tid >> 6, quad = lane >> 4, l15 = lane & 15;
    const int m0 = blockIdx.x * 128, n0 = blockIdx.y * 128;

#pragma unroll
    for (int p = 0; p < 16; p++) {
        int g = p * 256 + tid;
        int ch = g >> 9, rem = g & 511, nt = rem >> 6, L = rem & 63;
        const float* src = &W[(size_t)(n0 + nt * 16 + (L & 15)) * D_ + ch * 32 + ((L >> 4) & 3) * 8];
        float4 w0 = *(const float4*)src;
        float4 w1 = *(const float4*)(src + 4);
        half8_t hv = {(_Float16)w0.x, (_Float16)w0.y, (_Float16)w0.z, (_Float16)w0.w,
                      (_Float16)w1.x, (_Float16)w1.y, (_Float16)w1.z, (_Float16)w1.w};
        *(half8_t*)&fw[g * 8] = hv;
    }
    __syncthreads();

    f32x4 acc[2][8] = {};
    const _Float16* Ar0 = &A[(size_t)(m0 + w * 16 + l15) * D_];
    const _Float16* Ar1 = Ar0 + (size_t)64 * D_;
#pragma unroll
    for (int ch = 0; ch < 8; ch++) {
        half8_t af0 = *(const half8_t*)&Ar0[ch * 32 + quad * 8];
        half8_t af1 = *(const half8_t*)&Ar1[ch * 32 + quad * 8];
#pragma unroll
        for (int nt = 0; nt < 8; nt++) {
            half8_t bf = *(const half8_t*)&fw[((ch * 8 + nt) * 64 + lane) * 8];
            acc[0][nt] = __builtin_amdgcn_mfma_f32_16x16x32_f16(af0, bf, acc[0][nt], 0, 0, 0);
            acc[1][nt] = __builtin_amdgcn_mfma_f32_16x16x32_f16(af1, bf, acc[1][nt], 0, 0, 0);
        }
    }
#pragma unroll
    for (int mt = 0; mt < 2; mt++) {
        int mbase = m0 + mt * 64 + w * 16 + quad * 4;
#pragma unroll
        for (int nt = 0; nt < 8; nt++) {
            int n = n0 + nt * 16 + l15;
#pragma unroll
            for (int r = 0; r < 4; r++)
                out[(size_t)(mbase + r) * D_ + n] = acc[mt][nt][r];
        }
    }
}

// ---------------------------------------------------------------------------
extern "C" void kernel_launch(void* const* d_in, const int* in_sizes, int n_in,
                              void* d_out, int out_size, void* d_ws, size_t ws_size,
                              hipStream_t stream)
{
    const float* q_tokens = (const float*)d_in[0];
    const float* k_tokens = (const float*)d_in[1];
    const float* v_tokens = (const float*)d_in[2];
    const int*   t_q      = (const int*)d_in[3];
    const int*   f_q      = (const int*)d_in[4];
    const int*   t_k      = (const int*)d_in[5];
    const int*   f_k      = (const int*)d_in[6];
    // d_in[7]=N_t, d_in[8]=N_f hardcoded
    const float* W_q   = (const float*)d_in[9];
    const float* W_k   = (const float*)d_in[10];
    const float* W_v   = (const float*)d_in[11];
    const float* W_o   = (const float*)d_in[12];
    const float* W_rpe = (const float*)d_in[13];

    // ws layout (fp16): Qa/Ka [bh][n][64] augmented, Vt [bh][32][n], AO [b][q][256]
    _Float16* ws = (_Float16*)d_ws;
    _Float16* Qa = ws;                       // 64*1008*64
    _Float16* Ka = Qa + (size_t)64 * N_ * DA_;
    _Float16* Vt = Ka + (size_t)64 * N_ * DA_;  // 64*32*1008
    _Float16* AO = Vt + (size_t)64 * DK_ * N_;  // 8064*256

    prep_kernel<<<dim3(284), 256, 0, stream>>>(t_q, f_q, t_k, f_k, W_rpe, Qa, Ka);
    qkv_gemm<<<dim3(63, 2, 3), 256, 0, stream>>>(q_tokens, k_tokens, v_tokens,
                                                 W_q, W_k, W_v, Qa, Ka, Vt);
    attn<<<dim3(16, 64), 256, 0, stream>>>(Qa, Ka, Vt, AO);
    out_gemm<<<dim3(63, 2), 256, 0, stream>>>(AO, W_o, (float*)d_out);
}